// Round 1
// baseline (178.208 us; speedup 1.0000x reference)
//
#include <hip/hip_runtime.h>

// Shapes from reference: x = (B,1,1024,1024) fp32, grid=8, bins=256, clip=40.
// Pre-CLAHE chain (normalize -> standardize -> normalize) collapses exactly to
// (x - min) / (max - min), so we only need global min/max + CLAHE.

#define BINS 256
#define TH 128
#define PIXELS 16384      // 128*128
#define MAXV 2560u        // int(40 * 16384 / 256)

// monotone float<->uint encoding for atomic min/max
__device__ __forceinline__ unsigned fenc(float f){
  unsigned u = __float_as_uint(f);
  return (u & 0x80000000u) ? ~u : (u | 0x80000000u);
}
__device__ __forceinline__ float fdec(unsigned e){
  unsigned u = (e & 0x80000000u) ? (e & 0x7FFFFFFFu) : ~e;
  return __uint_as_float(u);
}

__global__ void k_init(unsigned* mm){
  mm[0] = 0xFFFFFFFFu;  // running-min slot (encoded +inf side)
  mm[1] = 0u;           // running-max slot (encoded -inf side)
}

__global__ __launch_bounds__(256) void k_minmax(const float4* __restrict__ x4,
                                                unsigned* mm, int n4){
  int tid = blockIdx.x * blockDim.x + threadIdx.x;
  int stride = gridDim.x * blockDim.x;
  float lmin = INFINITY, lmax = -INFINITY;
  for (int i = tid; i < n4; i += stride){
    float4 v = x4[i];
    lmin = fminf(lmin, fminf(fminf(v.x, v.y), fminf(v.z, v.w)));
    lmax = fmaxf(lmax, fmaxf(fmaxf(v.x, v.y), fmaxf(v.z, v.w)));
  }
  for (int o = 32; o > 0; o >>= 1){
    lmin = fminf(lmin, __shfl_down(lmin, o, 64));
    lmax = fmaxf(lmax, __shfl_down(lmax, o, 64));
  }
  __shared__ float smin[4], smax[4];
  int lane = threadIdx.x & 63, wv = threadIdx.x >> 6;
  if (lane == 0){ smin[wv] = lmin; smax[wv] = lmax; }
  __syncthreads();
  if (threadIdx.x == 0){
    float m = smin[0], M = smax[0];
    #pragma unroll
    for (int i = 1; i < 4; i++){ m = fminf(m, smin[i]); M = fmaxf(M, smax[i]); }
    atomicMin(&mm[0], fenc(m));
    atomicMax(&mm[1], fenc(M));
  }
}

// one block per 128x128 tile: histogram -> clip -> residual -> scan -> LUT
__global__ __launch_bounds__(256) void k_hist(const float* __restrict__ x,
                                              const unsigned* __restrict__ mm,
                                              float* __restrict__ lut){
  __shared__ unsigned hist[BINS];
  __shared__ unsigned wsum[4];
  __shared__ unsigned sc[BINS];
  int t = threadIdx.x;
  hist[t] = 0u;
  float mn = fdec(mm[0]);
  float inv = 1.0f / (fdec(mm[1]) - mn);
  int tile = blockIdx.x;
  int bc = tile >> 6, ti = (tile >> 3) & 7, tj = tile & 7;
  const float4* x4 = (const float4*)(x + ((size_t)bc * 1024 + ti * TH) * 1024 + tj * TH);
  __syncthreads();
  #pragma unroll 4
  for (int k = 0; k < 16; k++){
    int p = t + (k << 8);           // vec index within tile, 32 float4 per row
    int row = p >> 5, col = p & 31;
    float4 v = x4[row * 256 + col];
    int b0 = min(max((int)(((v.x - mn) * inv) * 256.0f), 0), 255);
    int b1 = min(max((int)(((v.y - mn) * inv) * 256.0f), 0), 255);
    int b2 = min(max((int)(((v.z - mn) * inv) * 256.0f), 0), 255);
    int b3 = min(max((int)(((v.w - mn) * inv) * 256.0f), 0), 255);
    atomicAdd(&hist[b0], 1u);
    atomicAdd(&hist[b1], 1u);
    atomicAdd(&hist[b2], 1u);
    atomicAdd(&hist[b3], 1u);
  }
  __syncthreads();
  unsigned h = hist[t];
  if (h > MAXV) h = MAXV;
  // total of clipped hist
  unsigned s = h;
  for (int o = 32; o > 0; o >>= 1) s += __shfl_down(s, o, 64);
  int lane = t & 63, wv = t >> 6;
  if (lane == 0) wsum[wv] = s;
  __syncthreads();
  unsigned total = wsum[0] + wsum[1] + wsum[2] + wsum[3];
  float residual = ((float)PIXELS - (float)total) * (1.0f / 256.0f);
  // inclusive scan (Hillis-Steele) over 256 bins
  sc[t] = h;
  __syncthreads();
  for (int o = 1; o < 256; o <<= 1){
    unsigned v = (t >= o) ? sc[t - o] : 0u;
    __syncthreads();
    sc[t] += v;
    __syncthreads();
  }
  float cum = ((float)sc[t] + (float)(t + 1) * residual) * (255.0f / 16384.0f);
  lut[(size_t)tile * BINS + t] = floorf(fminf(fmaxf(cum, 0.0f), 255.0f));
}

// one block = one image row (256 threads x float4 = 1024 px) -> i0/i1/wy uniform
__global__ __launch_bounds__(256) void k_apply(const float* __restrict__ x,
                                               const unsigned* __restrict__ mm,
                                               const float* __restrict__ lut,
                                               float* __restrict__ out, int n4){
  int iv = blockIdx.x * 256 + threadIdx.x;
  if (iv >= n4) return;
  float mn = fdec(mm[0]);
  float inv = 1.0f / (fdec(mm[1]) - mn);
  int i = iv << 2;
  int b = i >> 20;            // H*W = 2^20
  int h = (i >> 10) & 1023;
  int w0 = i & 1023;
  float gi = fminf(fmaxf((h + 0.5f) * (1.0f / 128.0f) - 0.5f, 0.0f), 7.0f);
  int i0 = (int)gi;
  int i1 = min(i0 + 1, 7);
  float wy = gi - (float)i0;
  const float* lb = lut + (size_t)b * 64 * BINS;   // C == 1
  const float* l0 = lb + i0 * 8 * BINS;
  const float* l1 = lb + i1 * 8 * BINS;
  float4 xv = ((const float4*)x)[iv];
  float xs[4] = {xv.x, xv.y, xv.z, xv.w};
  float r[4];
  #pragma unroll
  for (int c = 0; c < 4; c++){
    float v = (xs[c] - mn) * inv;
    int bi = min(max((int)(v * 256.0f), 0), 255);
    float gj = fminf(fmaxf((w0 + c + 0.5f) * (1.0f / 128.0f) - 0.5f, 0.0f), 7.0f);
    int j0 = (int)gj;
    int j1 = min(j0 + 1, 7);
    float wx = gj - (float)j0;
    float v00 = l0[j0 * BINS + bi];
    float v01 = l0[j1 * BINS + bi];
    float v10 = l1[j0 * BINS + bi];
    float v11 = l1[j1 * BINS + bi];
    r[c] = ((1.0f - wy) * ((1.0f - wx) * v00 + wx * v01) +
            wy * ((1.0f - wx) * v10 + wx * v11)) * (1.0f / 255.0f);
  }
  ((float4*)out)[iv] = make_float4(r[0], r[1], r[2], r[3]);
}

__global__ void k_tail(const int* __restrict__ y, float* __restrict__ out,
                       int n, int tail){
  int t = threadIdx.x;
  if (t < tail) out[n + t] = (float)y[t];
}

extern "C" void kernel_launch(void* const* d_in, const int* in_sizes, int n_in,
                              void* d_out, int out_size, void* d_ws, size_t ws_size,
                              hipStream_t stream){
  const float* x = (const float*)d_in[0];
  const int* y = (const int*)d_in[1];
  float* out = (float*)d_out;
  int N = in_sizes[0];           // B*1*1024*1024
  int B = N >> 20;
  int n4 = N >> 2;
  unsigned* mm = (unsigned*)d_ws;
  float* lut = (float*)((char*)d_ws + 256);

  hipLaunchKernelGGL(k_init, dim3(1), dim3(1), 0, stream, mm);
  hipLaunchKernelGGL(k_minmax, dim3(1024), dim3(256), 0, stream,
                     (const float4*)x, mm, n4);
  hipLaunchKernelGGL(k_hist, dim3(B * 64), dim3(256), 0, stream, x, mm, lut);
  hipLaunchKernelGGL(k_apply, dim3(n4 / 256), dim3(256), 0, stream,
                     x, mm, lut, out, n4);
  int tail = out_size - N;
  if (tail > 0){
    hipLaunchKernelGGL(k_tail, dim3(1), dim3(64), 0, stream, y, out, N, tail);
  }
}

// Round 2
// 156.652 us; speedup vs baseline: 1.1376x; 1.1376x over previous
//
#include <hip/hip_runtime.h>

// x = (B,1,1024,1024) fp32. Pre-CLAHE chain collapses exactly to
// (x - min)/(max - min). Pipeline: init+tail -> minmax -> hist(+bins u8) -> apply.

#define BINS 256
#define MAXV 2560u        // int(40 * 16384 / 256)

__device__ __forceinline__ unsigned fenc(float f){
  unsigned u = __float_as_uint(f);
  return (u & 0x80000000u) ? ~u : (u | 0x80000000u);
}
__device__ __forceinline__ float fdec(unsigned e){
  unsigned u = (e & 0x80000000u) ? (e & 0x7FFFFFFFu) : ~e;
  return __uint_as_float(u);
}

__global__ void k_init(unsigned* mm, const int* __restrict__ y,
                       float* __restrict__ out, int N, int tail){
  int t = threadIdx.x;
  if (t == 0){ mm[0] = 0xFFFFFFFFu; mm[1] = 0u; }
  if (t < tail) out[N + t] = (float)y[t];
}

__global__ __launch_bounds__(256) void k_minmax(const float4* __restrict__ x4,
                                                unsigned* mm, int n4){
  int tid = blockIdx.x * blockDim.x + threadIdx.x;
  int stride = gridDim.x * blockDim.x;
  float lmin = INFINITY, lmax = -INFINITY;
  for (int i = tid; i < n4; i += stride){
    float4 v = x4[i];
    lmin = fminf(lmin, fminf(fminf(v.x, v.y), fminf(v.z, v.w)));
    lmax = fmaxf(lmax, fmaxf(fmaxf(v.x, v.y), fmaxf(v.z, v.w)));
  }
  for (int o = 32; o > 0; o >>= 1){
    lmin = fminf(lmin, __shfl_down(lmin, o, 64));
    lmax = fmaxf(lmax, __shfl_down(lmax, o, 64));
  }
  __shared__ float smin[4], smax[4];
  int lane = threadIdx.x & 63, wv = threadIdx.x >> 6;
  if (lane == 0){ smin[wv] = lmin; smax[wv] = lmax; }
  __syncthreads();
  if (threadIdx.x == 0){
    float m = smin[0], M = smax[0];
    #pragma unroll
    for (int i = 1; i < 4; i++){ m = fminf(m, smin[i]); M = fmaxf(M, smax[i]); }
    atomicMin(&mm[0], fenc(m));
    atomicMax(&mm[1], fenc(M));
  }
}

// one block per 128x128 tile: 8-copy privatized histogram (stride 257 so the
// same bin in different copies hits different banks) -> clip -> residual ->
// scan -> LUT. Optionally writes u8 bin indices for k_apply.
__global__ __launch_bounds__(256) void k_hist(const float* __restrict__ x,
                                              const unsigned* __restrict__ mm,
                                              float* __restrict__ lut,
                                              unsigned char* __restrict__ bins){
  __shared__ unsigned hist8[8 * 257];
  __shared__ unsigned wsum[4];
  __shared__ unsigned sc[BINS];
  int t = threadIdx.x;
  for (int i = t; i < 8 * 257; i += 256) hist8[i] = 0u;
  float mn = fdec(mm[0]);
  float inv = 1.0f / (fdec(mm[1]) - mn);
  int tile = blockIdx.x;
  int bc = tile >> 6, ti = (tile >> 3) & 7, tj = tile & 7;
  size_t base = ((size_t)bc * 1024 + ti * 128) * 1024 + tj * 128;
  const float4* x4 = (const float4*)(x + base);
  uchar4* b4 = bins ? (uchar4*)(bins + base) : nullptr;
  unsigned hc = (t & 7) * 257;
  __syncthreads();
  #pragma unroll 4
  for (int k = 0; k < 16; k++){
    int p = t + (k << 8);           // 32 float4 per 128-px row
    int row = p >> 5, col = p & 31;
    float4 v = x4[row * 256 + col];
    int b0 = min(max((int)(((v.x - mn) * inv) * 256.0f), 0), 255);
    int b1 = min(max((int)(((v.y - mn) * inv) * 256.0f), 0), 255);
    int b2 = min(max((int)(((v.z - mn) * inv) * 256.0f), 0), 255);
    int b3 = min(max((int)(((v.w - mn) * inv) * 256.0f), 0), 255);
    if (b4) b4[row * 256 + col] = make_uchar4((unsigned char)b0, (unsigned char)b1,
                                              (unsigned char)b2, (unsigned char)b3);
    atomicAdd(&hist8[hc + b0], 1u);
    atomicAdd(&hist8[hc + b1], 1u);
    atomicAdd(&hist8[hc + b2], 1u);
    atomicAdd(&hist8[hc + b3], 1u);
  }
  __syncthreads();
  unsigned h = 0;
  #pragma unroll
  for (int c = 0; c < 8; c++) h += hist8[c * 257 + t];
  if (h > MAXV) h = MAXV;
  unsigned s = h;
  for (int o = 32; o > 0; o >>= 1) s += __shfl_down(s, o, 64);
  int lane = t & 63, wv = t >> 6;
  if (lane == 0) wsum[wv] = s;
  __syncthreads();
  unsigned total = wsum[0] + wsum[1] + wsum[2] + wsum[3];
  float residual = (16384.0f - (float)total) * (1.0f / 256.0f);
  sc[t] = h;
  __syncthreads();
  for (int o = 1; o < 256; o <<= 1){
    unsigned v = (t >= o) ? sc[t - o] : 0u;
    __syncthreads();
    sc[t] += v;
    __syncthreads();
  }
  float cum = ((float)sc[t] + (float)(t + 1) * residual) * (255.0f / 16384.0f);
  lut[(size_t)tile * BINS + t] = floorf(fminf(fmaxf(cum, 0.0f), 255.0f));
}

// one block = 16-row strip of one image (i0/i1 uniform: band boundaries are
// 64-aligned). Stages both needed LUT rows (16 KB) in LDS; reads u8 bins if
// available, else recomputes from x.
__global__ __launch_bounds__(256) void k_apply(const float* __restrict__ x,
                                               const uchar4* __restrict__ binsq,
                                               const unsigned* __restrict__ mm,
                                               const float* __restrict__ lutg,
                                               float* __restrict__ out){
  __shared__ float l0s[2048];
  __shared__ float l1s[2048];
  int t = threadIdx.x;
  int strip = blockIdx.x;
  int b = strip >> 6;
  int r0 = (strip & 63) << 4;
  float gi = fminf(fmaxf((r0 + 0.5f) * (1.0f / 128.0f) - 0.5f, 0.0f), 7.0f);
  int i0 = (int)gi;
  int i1 = min(i0 + 1, 7);
  const float4* g0 = (const float4*)(lutg + ((size_t)b * 8 + i0) * 2048);
  const float4* g1 = (const float4*)(lutg + ((size_t)b * 8 + i1) * 2048);
  ((float4*)l0s)[t]       = g0[t];
  ((float4*)l0s)[t + 256] = g0[t + 256];
  ((float4*)l1s)[t]       = g1[t];
  ((float4*)l1s)[t + 256] = g1[t + 256];
  int j0[4], j1[4];
  float wx[4];
  #pragma unroll
  for (int c = 0; c < 4; c++){
    int col = (t << 2) + c;
    float gj = fminf(fmaxf((col + 0.5f) * (1.0f / 128.0f) - 0.5f, 0.0f), 7.0f);
    j0[c] = (int)gj;
    j1[c] = min(j0[c] + 1, 7);
    wx[c] = gj - (float)j0[c];
  }
  float mn = 0.0f, inv = 0.0f;
  if (!binsq){ mn = fdec(mm[0]); inv = 1.0f / (fdec(mm[1]) - mn); }
  size_t base4 = ((size_t)b * 1024 + r0) * 256;   // float4 units
  __syncthreads();
  for (int r = 0; r < 16; r++){
    int h = r0 + r;
    float giw = fminf(fmaxf((h + 0.5f) * (1.0f / 128.0f) - 0.5f, 0.0f), 7.0f);
    float wy = giw - (float)i0;
    int bi[4];
    if (binsq){
      uchar4 bv = binsq[base4 + r * 256 + t];
      bi[0] = bv.x; bi[1] = bv.y; bi[2] = bv.z; bi[3] = bv.w;
    } else {
      float4 xv = ((const float4*)x)[base4 + r * 256 + t];
      bi[0] = min(max((int)(((xv.x - mn) * inv) * 256.0f), 0), 255);
      bi[1] = min(max((int)(((xv.y - mn) * inv) * 256.0f), 0), 255);
      bi[2] = min(max((int)(((xv.z - mn) * inv) * 256.0f), 0), 255);
      bi[3] = min(max((int)(((xv.w - mn) * inv) * 256.0f), 0), 255);
    }
    float res[4];
    #pragma unroll
    for (int c = 0; c < 4; c++){
      float v00 = l0s[(j0[c] << 8) + bi[c]];
      float v01 = l0s[(j1[c] << 8) + bi[c]];
      float v10 = l1s[(j0[c] << 8) + bi[c]];
      float v11 = l1s[(j1[c] << 8) + bi[c]];
      float top = v00 + wx[c] * (v01 - v00);
      float bot = v10 + wx[c] * (v11 - v10);
      res[c] = (top + wy * (bot - top)) * (1.0f / 255.0f);
    }
    ((float4*)out)[base4 + r * 256 + t] = make_float4(res[0], res[1], res[2], res[3]);
  }
}

extern "C" void kernel_launch(void* const* d_in, const int* in_sizes, int n_in,
                              void* d_out, int out_size, void* d_ws, size_t ws_size,
                              hipStream_t stream){
  const float* x = (const float*)d_in[0];
  const int* y = (const int*)d_in[1];
  float* out = (float*)d_out;
  int N = in_sizes[0];
  int B = N >> 20;
  int n4 = N >> 2;
  unsigned* mm = (unsigned*)d_ws;
  float* lut = (float*)((char*)d_ws + 256);
  size_t lutbytes = (size_t)B * 64 * 256 * 4;
  unsigned char* bins = (unsigned char*)d_ws + 256 + lutbytes;
  bool use_bins = ws_size >= 256 + lutbytes + (size_t)N;
  int tail = out_size - N;

  hipLaunchKernelGGL(k_init, dim3(1), dim3(64), 0, stream, mm, y, out, N, tail);
  hipLaunchKernelGGL(k_minmax, dim3(1024), dim3(256), 0, stream,
                     (const float4*)x, mm, n4);
  hipLaunchKernelGGL(k_hist, dim3(B * 64), dim3(256), 0, stream,
                     x, mm, lut, use_bins ? bins : nullptr);
  hipLaunchKernelGGL(k_apply, dim3(B * 64), dim3(256), 0, stream,
                     x, use_bins ? (const uchar4*)bins : nullptr, mm, lut, out);
}